// Round 2
// baseline (582.510 us; speedup 1.0000x reference)
//
#include <hip/hip_runtime.h>
#include <stdint.h>

#define T_STEPS 512
#define BATCH   32
#define DIMN    1024
#define MROWS   (T_STEPS*BATCH)   // 16384
#define BD      (BATCH*DIMN)      // 32768

typedef _Float16 f16;
typedef _Float16 f16x8 __attribute__((ext_vector_type(8)));
typedef _Float16 f16x4 __attribute__((ext_vector_type(4)));
typedef _Float16 f16x2 __attribute__((ext_vector_type(2)));
typedef float    f32x4 __attribute__((ext_vector_type(4)));

union U8 { f16x8 v; f16x2 p[4]; };

// packed f32x2 -> f16x2 (RTZ), bit-cast to our _Float16 vector type
__device__ __forceinline__ f16x2 pkrtz(float a, float b) {
  return __builtin_bit_cast(f16x2, __builtin_amdgcn_cvt_pkrtz(a, b));
}

// ---------- async global -> LDS, 16 B per lane ----------
__device__ __forceinline__ void load16_to_lds(const f16* gptr, f16* lptr) {
  __builtin_amdgcn_global_load_lds(
      (const __attribute__((address_space(1))) unsigned int*)(uintptr_t)gptr,
      (__attribute__((address_space(3))) unsigned int*)(uint32_t)(uintptr_t)lptr,
      16, 0, 0);
}

// ---------- DPP row-rotate add ----------
template<int CTRL>
__device__ __forceinline__ float dpp_ror_add(float v) {
  int iv = __float_as_int(v);
  int rv = __builtin_amdgcn_update_dpp(iv, iv, CTRL, 0xF, 0xF, false);
  return v + __int_as_float(rv);
}

// all-lanes sum of 64 lanes: 4 DPP row-ror adds (row sums) + readlane x4 + 3 adds.
__device__ __forceinline__ float wave_allsum(float s) {
  s = dpp_ror_add<0x128>(s);   // row_ror:8
  s = dpp_ror_add<0x124>(s);   // row_ror:4
  s = dpp_ror_add<0x122>(s);   // row_ror:2
  s = dpp_ror_add<0x121>(s);   // row_ror:1 -> each lane: sum of its 16-lane row
  float a = __int_as_float(__builtin_amdgcn_readlane(__float_as_int(s), 0));
  float b = __int_as_float(__builtin_amdgcn_readlane(__float_as_int(s), 16));
  float c = __int_as_float(__builtin_amdgcn_readlane(__float_as_int(s), 32));
  float d = __int_as_float(__builtin_amdgcn_readlane(__float_as_int(s), 48));
  return (a + b) + (c + d);
}

// ---------- f32 -> f16 convert, 8 elems/thread ----------
__global__ __launch_bounds__(256) void cvt_f32_f16(const float* __restrict__ src,
                                                   f16* __restrict__ dst, int n8) {
  int i = blockIdx.x * 256 + threadIdx.x;
  if (i >= n8) return;
  const float4* s = (const float4*)src;
  float4 a = s[2*i], b = s[2*i + 1];
  f16x8 o = { (f16)a.x, (f16)a.y, (f16)a.z, (f16)a.w,
              (f16)b.x, (f16)b.y, (f16)b.z, (f16)b.w };
  *(f16x8*)(dst + (size_t)i * 8) = o;
}

// ---------- 128x128-tile fp16 MFMA GEMM ----------
// mode 0: Cout = (f16)( exp(la)      * (acc + bias[n]) )
// mode 1: Cout = (f16)( addend[m,n] + 0.1*sigmoid(lb)*rowscale[m]*acc )
__global__ __launch_bounds__(256) void gemm_bt_f16(
    const f16* __restrict__ A, const f16* __restrict__ B,
    const float* __restrict__ bias, f16* __restrict__ Cout,
    const float* __restrict__ la, const float* __restrict__ lb,
    const float* __restrict__ rowscale, const f16* __restrict__ addend, int mode) {
  constexpr int K = DIMN;
  constexpr int N = DIMN;
  __shared__ f16 Alds[128 * 32];
  __shared__ f16 Blds[128 * 32];
  const int tid  = threadIdx.x;
  const int lane = tid & 63;
  const int wid  = tid >> 6;
  const int wm = wid & 1, wn = wid >> 1;       // 2x2 waves -> 64x64 each
  const int l15  = lane & 15;
  const int quad = lane >> 4;
  const int swz  = (l15 >> 1) & 3;
  const int rowBase = blockIdx.x * 128;        // M
  const int colBase = blockIdx.y * 128;        // N
  const int sr = lane >> 2;
  const int cs = lane & 3;

  const float scale = (mode == 0) ? expf(la[0])
                                  : 0.1f / (1.0f + expf(-lb[0]));

  f32x4 acc[4][4] = {};

  for (int k0 = 0; k0 < K; k0 += 32) {
    #pragma unroll
    for (int i = 0; i < 2; ++i) {
      const int g = wid + i * 4;
      const int r = g * 16 + sr;
      const int cd = cs ^ ((r >> 1) & 3);
      load16_to_lds(A + (size_t)(rowBase + r) * K + k0 + cd * 8, Alds + g * 512);
      load16_to_lds(B + (size_t)(colBase + r) * K + k0 + cd * 8, Blds + g * 512);
    }
    __syncthreads();
    f16x8 af[4], bf[4];
    #pragma unroll
    for (int mi = 0; mi < 4; ++mi) {
      const int r = wm * 64 + mi * 16 + l15;
      af[mi] = *(const f16x8*)(Alds + r * 32 + (quad ^ swz) * 8);
    }
    #pragma unroll
    for (int ni = 0; ni < 4; ++ni) {
      const int r = wn * 64 + ni * 16 + l15;
      bf[ni] = *(const f16x8*)(Blds + r * 32 + (quad ^ swz) * 8);
    }
    #pragma unroll
    for (int mi = 0; mi < 4; ++mi)
      #pragma unroll
      for (int ni = 0; ni < 4; ++ni)
        acc[mi][ni] = __builtin_amdgcn_mfma_f32_16x16x32_f16(af[mi], bf[ni], acc[mi][ni], 0, 0, 0);
    __syncthreads();
  }

  float colb[4];
  #pragma unroll
  for (int ni = 0; ni < 4; ++ni)
    colb[ni] = (mode == 0) ? bias[colBase + wn * 64 + ni * 16 + l15] : 0.0f;

  #pragma unroll
  for (int mi = 0; mi < 4; ++mi) {
    const int m0 = rowBase + wm * 64 + mi * 16 + quad * 4;
    #pragma unroll
    for (int j = 0; j < 4; ++j) {
      const size_t row = (size_t)(m0 + j);
      const float rs = (mode == 0) ? scale : scale * rowscale[row];
      #pragma unroll
      for (int ni = 0; ni < 4; ++ni) {
        const int n = colBase + wn * 64 + ni * 16 + l15;
        float v;
        if (mode == 0) v = rs * (acc[mi][ni][j] + colb[ni]);
        else           v = fmaf(rs, acc[mi][ni][j], (float)addend[row * N + n]);
        Cout[row * N + n] = (f16)v;
      }
    }
  }
}

// ---------- scan: h_{t+1} = rmsnorm(h_t + w_t), in scaled frame u = c*h ----------
// Stores u (fp16) + per-row inverse scale ic (so consumers apply h = u*ic).
// SHIFT=1 (pass 0): G[t+1] = u_{t+1} (skip t=511), G[0] = h0, S[0] = 1.
// SHIFT=0 (pass 1): G[t]   = u_{t+1}, all t.
template<int SHIFT>
__global__ __launch_bounds__(64) void scan_wave(
    const f16* __restrict__ Win,       // [T,B,D] effective additive input, fp16
    const float* __restrict__ h0,
    f16* __restrict__ G,               // unnormalized states u
    float* __restrict__ S) {           // per-row scale ic = 1/c
  const int b = blockIdx.x;
  const int l = threadIdx.x;
  const size_t base = (size_t)b * DIMN + (size_t)l * 8;

  float u[16];
  {
    float4 a0 = *(const float4*)(h0 + base);
    float4 a1 = *(const float4*)(h0 + base + 4);
    float4 a2 = *(const float4*)(h0 + base + 512);
    float4 a3 = *(const float4*)(h0 + base + 516);
    u[0]=a0.x; u[1]=a0.y; u[2]=a0.z; u[3]=a0.w;
    u[4]=a1.x; u[5]=a1.y; u[6]=a1.z; u[7]=a1.w;
    u[8]=a2.x; u[9]=a2.y; u[10]=a2.z; u[11]=a2.w;
    u[12]=a3.x; u[13]=a3.y; u[14]=a3.z; u[15]=a3.w;
    if (SHIFT) {
      f16x8 g0, g1;
      #pragma unroll
      for (int i = 0; i < 8; ++i) { g0[i] = (f16)u[i]; g1[i] = (f16)u[i+8]; }
      *(f16x8*)(G + base) = g0;
      *(f16x8*)(G + base + 512) = g1;
      if (l == 0) S[b] = 1.0f;
    }
  }

  float c  = 1.0f;            // u = c * h
  float ic = 1.0f;            // 1/c
  float kk = 1.0f / DIMN;     // ic^2 / D

  U8 bw0[8], bw1[8];
  #pragma unroll
  for (int j = 0; j < 8; ++j) {
    bw0[j].v = *(const f16x8*)(Win + (size_t)j * BD + base);
    bw1[j].v = *(const f16x8*)(Win + (size_t)j * BD + base + 512);
  }

  for (int tb = 0; tb < T_STEPS; tb += 8) {
    #pragma unroll
    for (int j = 0; j < 8; ++j) {
      const int t = tb + j;
      U8 w0 = bw0[j], w1 = bw1[j];
      int tn = t + 8; if (tn > T_STEPS - 1) tn = T_STEPS - 1;
      bw0[j].v = *(const f16x8*)(Win + (size_t)tn * BD + base);
      bw1[j].v = *(const f16x8*)(Win + (size_t)tn * BD + base + 512);
      // u += c * w   (the only chain dependency on the previous step's scalar)
      #pragma unroll
      for (int i = 0; i < 8; ++i) {
        u[i]   = fmaf(c, (float)w0.v[i], u[i]);
        u[i+8] = fmaf(c, (float)w1.v[i], u[i+8]);
      }
      float s0 = 0.f, s1 = 0.f, s2 = 0.f, s3 = 0.f;
      #pragma unroll
      for (int i = 0; i < 4; ++i) {
        s0 = fmaf(u[i],    u[i],    s0);
        s1 = fmaf(u[i+4],  u[i+4],  s1);
        s2 = fmaf(u[i+8],  u[i+8],  s2);
        s3 = fmaf(u[i+12], u[i+12], s3);
      }
      const float Q   = wave_allsum((s0 + s1) + (s2 + s3));
      const float m   = fmaf(Q, kk, 1e-6f);          // mean(v^2) + eps
      const float rho = __builtin_amdgcn_rsqf(m);    // v_rsq_f32
      c  = c * (m * rho);                            // c *= sqrt(m)
      ic = ic * rho;
      kk = kk * (rho * rho);
      if (SHIFT == 0 || t < T_STEPS - 1) {
        U8 g0, g1;
        #pragma unroll
        for (int i = 0; i < 4; ++i) {
          g0.p[i] = pkrtz(u[2*i],   u[2*i+1]);
          g1.p[i] = pkrtz(u[2*i+8], u[2*i+9]);
        }
        const size_t off = (size_t)(t + SHIFT) * BD + base;
        *(f16x8*)(G + off) = g0.v;
        *(f16x8*)(G + off + 512) = g1.v;
        if (l == 0) S[(t + SHIFT) * BATCH + b] = ic;
      }
    }
  }
}

// ---------- expand: g = u*ic; outs[t] = g*g*sigmoid(g), hout[t+1] = g; hout[0] = h0 ----------
__global__ __launch_bounds__(256) void expand_kernel(
    const f16* __restrict__ G1, const float* __restrict__ S1v,
    const float* __restrict__ h0,
    float* __restrict__ outs, float* __restrict__ hout) {
  const long long total8 = (long long)T_STEPS * BD / 8;
  const long long idx = (long long)blockIdx.x * 256 + threadIdx.x;
  if (idx < total8) {
    const size_t e = (size_t)idx * 8;
    f16x8 g = *(const f16x8*)(G1 + e);
    const float s = S1v[e >> 10];        // row scale ic (D = 1024)
    float v[8], o[8];
    #pragma unroll
    for (int i = 0; i < 8; ++i) v[i] = (float)g[i] * s;
    #pragma unroll
    for (int i = 0; i < 8; ++i) o[i] = v[i] * v[i] / (1.0f + expf(-v[i]));
    *(float4*)(hout + BD + e)     = make_float4(v[0], v[1], v[2], v[3]);
    *(float4*)(hout + BD + e + 4) = make_float4(v[4], v[5], v[6], v[7]);
    *(float4*)(outs + e)     = make_float4(o[0], o[1], o[2], o[3]);
    *(float4*)(outs + e + 4) = make_float4(o[4], o[5], o[6], o[7]);
  } else {
    const size_t j = (size_t)(idx - total8) * 8;
    if (j < (size_t)BD) {
      float4 a0 = *(const float4*)(h0 + j);
      float4 a1 = *(const float4*)(h0 + j + 4);
      *(float4*)(hout + j)     = a0;
      *(float4*)(hout + j + 4) = a1;
    }
  }
}

extern "C" void kernel_launch(void* const* d_in, const int* in_sizes, int n_in,
                              void* d_out, int out_size, void* d_ws, size_t ws_size,
                              hipStream_t stream) {
  const float* x    = (const float*)d_in[0];
  const float* h0   = (const float*)d_in[1];
  const float* W    = (const float*)d_in[2];
  const float* Wh   = (const float*)d_in[3];
  const float* bias = (const float*)d_in[4];
  const float* la   = (const float*)d_in[5];
  const float* lb   = (const float*)d_in[6];

  char* ws = (char*)d_ws;
  f16* XH   = (f16*)(ws);
  f16* W16  = (f16*)(ws + 33554432ull);
  f16* WH16 = (f16*)(ws + 35651584ull);
  f16* WX16 = (f16*)(ws + 37748736ull);
  f16* G0   = (f16*)(ws + 71303168ull);
  f16* C16  = (f16*)(ws + 104857600ull);
  f16* G1   = XH;                               // alias: XH dead after GEMM0
  // Row-scale vectors (64 KB each) reuse dead weight slots:
  // S0 overlaps W16  (W16 dead after GEMM0; S0 written by scan0, read by GEMM1)
  // S1 overlaps WH16 (WH16 dead after GEMM1; S1 written by scan1, read by expand)
  float* S0 = (float*)(ws + 33554432ull);
  float* S1 = (float*)(ws + 35651584ull);

  float* outs = (float*)d_out;
  float* hout = outs + (size_t)T_STEPS * BD;

  cvt_f32_f16<<<dim3((MROWS * DIMN / 8) / 256), 256, 0, stream>>>(x, XH, MROWS * DIMN / 8);
  cvt_f32_f16<<<dim3((DIMN * DIMN / 8) / 256), 256, 0, stream>>>(W, W16, DIMN * DIMN / 8);
  cvt_f32_f16<<<dim3((DIMN * DIMN / 8) / 256), 256, 0, stream>>>(Wh, WH16, DIMN * DIMN / 8);

  // WX16 = alpha * (x @ W^T + b)
  gemm_bt_f16<<<dim3(MROWS / 128, DIMN / 128), 256, 0, stream>>>(
      XH, W16, bias, WX16, la, lb, nullptr, nullptr, 0);

  // pass-0 scan: G0[t] = u0_t, S0[t*B+b] = ic0_t
  scan_wave<1><<<dim3(BATCH), 64, 0, stream>>>(WX16, h0, G0, S0);

  // C16 = WX16 + beta * ic0[row] * (G0 @ Wh^T)   (fused effective input for pass 1)
  gemm_bt_f16<<<dim3(MROWS / 128, DIMN / 128), 256, 0, stream>>>(
      G0, WH16, nullptr, C16, la, lb, S0, WX16, 1);

  // pass-1 scan: G1[t] = u1_{t+1}, S1[t*B+b] = ic1_{t+1}
  scan_wave<0><<<dim3(BATCH), 64, 0, stream>>>(C16, h0, G1, S1);

  // expand to fp32 outputs (applies ic row scale)
  const int total8 = T_STEPS * BD / 8;
  expand_kernel<<<dim3(total8 / 256 + 16), 256, 0, stream>>>(G1, S1, h0, outs, hout);
}

// Round 5
// 552.484 us; speedup vs baseline: 1.0543x; 1.0543x over previous
//
#include <hip/hip_runtime.h>
#include <stdint.h>

#define T_STEPS 512
#define BATCH   32
#define DIMN    1024
#define MROWS   (T_STEPS*BATCH)   // 16384
#define BD      (BATCH*DIMN)      // 32768

typedef _Float16 f16;
typedef _Float16 f16x8 __attribute__((ext_vector_type(8)));
typedef _Float16 f16x4 __attribute__((ext_vector_type(4)));
typedef _Float16 f16x2 __attribute__((ext_vector_type(2)));
typedef float    f32x4 __attribute__((ext_vector_type(4)));

union U8 { f16x8 v; f16x2 p[4]; };

// packed f32x2 -> f16x2 (RTZ), bit-cast to our _Float16 vector type
__device__ __forceinline__ f16x2 pkrtz(float a, float b) {
  return __builtin_bit_cast(f16x2, __builtin_amdgcn_cvt_pkrtz(a, b));
}

// ---------- async global -> LDS, 16 B per lane ----------
__device__ __forceinline__ void load16_to_lds(const f16* gptr, f16* lptr) {
  __builtin_amdgcn_global_load_lds(
      (const __attribute__((address_space(1))) unsigned int*)(uintptr_t)gptr,
      (__attribute__((address_space(3))) unsigned int*)(uint32_t)(uintptr_t)lptr,
      16, 0, 0);
}

// ---------- DPP row-rotate add ----------
template<int CTRL>
__device__ __forceinline__ float dpp_ror_add(float v) {
  int iv = __float_as_int(v);
  int rv = __builtin_amdgcn_update_dpp(iv, iv, CTRL, 0xF, 0xF, false);
  return v + __int_as_float(rv);
}

// all-lanes sum of 64 lanes: 4 DPP row-ror adds (row sums) + readlane x4 + 3 adds.
__device__ __forceinline__ float wave_allsum(float s) {
  s = dpp_ror_add<0x128>(s);   // row_ror:8
  s = dpp_ror_add<0x124>(s);   // row_ror:4
  s = dpp_ror_add<0x122>(s);   // row_ror:2
  s = dpp_ror_add<0x121>(s);   // row_ror:1 -> each lane: sum of its 16-lane row
  float a = __int_as_float(__builtin_amdgcn_readlane(__float_as_int(s), 0));
  float b = __int_as_float(__builtin_amdgcn_readlane(__float_as_int(s), 16));
  float c = __int_as_float(__builtin_amdgcn_readlane(__float_as_int(s), 32));
  float d = __int_as_float(__builtin_amdgcn_readlane(__float_as_int(s), 48));
  return (a + b) + (c + d);
}

// ---------- f32 -> f16 convert, 8 elems/thread ----------
__global__ __launch_bounds__(256) void cvt_f32_f16(const float* __restrict__ src,
                                                   f16* __restrict__ dst, int n8) {
  int i = blockIdx.x * 256 + threadIdx.x;
  if (i >= n8) return;
  const float4* s = (const float4*)src;
  float4 a = s[2*i], b = s[2*i + 1];
  f16x8 o = { (f16)a.x, (f16)a.y, (f16)a.z, (f16)a.w,
              (f16)b.x, (f16)b.y, (f16)b.z, (f16)b.w };
  *(f16x8*)(dst + (size_t)i * 8) = o;
}

// ---------- 128x128-tile fp16 MFMA GEMM ----------
// mode 0: Cout = (f16)( exp(la)      * (acc + bias[n]) )
// mode 1: Cout = (f16)( addend[m,n] + 0.1*sigmoid(lb)*rowscale_bmajor[m]*acc )
//   rowscale layout (mode 1): S[b][t], stride 512  (row m = t*BATCH + b)
__global__ __launch_bounds__(256) void gemm_bt_f16(
    const f16* __restrict__ A, const f16* __restrict__ B,
    const float* __restrict__ bias, f16* __restrict__ Cout,
    const float* __restrict__ la, const float* __restrict__ lb,
    const float* __restrict__ rowscale, const f16* __restrict__ addend, int mode) {
  constexpr int K = DIMN;
  constexpr int N = DIMN;
  __shared__ f16 Alds[128 * 32];
  __shared__ f16 Blds[128 * 32];
  const int tid  = threadIdx.x;
  const int lane = tid & 63;
  const int wid  = tid >> 6;
  const int wm = wid & 1, wn = wid >> 1;       // 2x2 waves -> 64x64 each
  const int l15  = lane & 15;
  const int quad = lane >> 4;
  const int swz  = (l15 >> 1) & 3;
  const int rowBase = blockIdx.x * 128;        // M
  const int colBase = blockIdx.y * 128;        // N
  const int sr = lane >> 2;
  const int cs = lane & 3;

  const float scale = (mode == 0) ? expf(la[0])
                                  : 0.1f / (1.0f + expf(-lb[0]));

  f32x4 acc[4][4] = {};

  for (int k0 = 0; k0 < K; k0 += 32) {
    #pragma unroll
    for (int i = 0; i < 2; ++i) {
      const int g = wid + i * 4;
      const int r = g * 16 + sr;
      const int cd = cs ^ ((r >> 1) & 3);
      load16_to_lds(A + (size_t)(rowBase + r) * K + k0 + cd * 8, Alds + g * 512);
      load16_to_lds(B + (size_t)(colBase + r) * K + k0 + cd * 8, Blds + g * 512);
    }
    __syncthreads();
    f16x8 af[4], bf[4];
    #pragma unroll
    for (int mi = 0; mi < 4; ++mi) {
      const int r = wm * 64 + mi * 16 + l15;
      af[mi] = *(const f16x8*)(Alds + r * 32 + (quad ^ swz) * 8);
    }
    #pragma unroll
    for (int ni = 0; ni < 4; ++ni) {
      const int r = wn * 64 + ni * 16 + l15;
      bf[ni] = *(const f16x8*)(Blds + r * 32 + (quad ^ swz) * 8);
    }
    #pragma unroll
    for (int mi = 0; mi < 4; ++mi)
      #pragma unroll
      for (int ni = 0; ni < 4; ++ni)
        acc[mi][ni] = __builtin_amdgcn_mfma_f32_16x16x32_f16(af[mi], bf[ni], acc[mi][ni], 0, 0, 0);
    __syncthreads();
  }

  float colb[4];
  #pragma unroll
  for (int ni = 0; ni < 4; ++ni)
    colb[ni] = (mode == 0) ? bias[colBase + wn * 64 + ni * 16 + l15] : 0.0f;

  #pragma unroll
  for (int mi = 0; mi < 4; ++mi) {
    const int m0 = rowBase + wm * 64 + mi * 16 + quad * 4;
    #pragma unroll
    for (int j = 0; j < 4; ++j) {
      const size_t row = (size_t)(m0 + j);
      const float rs = (mode == 0)
          ? scale
          : scale * rowscale[(((int)row & 31) << 9) | ((int)row >> 5)];
      #pragma unroll
      for (int ni = 0; ni < 4; ++ni) {
        const int n = colBase + wn * 64 + ni * 16 + l15;
        float v;
        if (mode == 0) v = rs * (acc[mi][ni][j] + colb[ni]);
        else           v = fmaf(rs, acc[mi][ni][j], (float)addend[row * N + n]);
        Cout[row * N + n] = (f16)v;
      }
    }
  }
}

// ---------- scan: h_{t+1} = rmsnorm(h_t + w_t), in scaled frame u = c*h ----------
// Stores u (fp16) + per-row inverse scale ic (consumers apply h = u*ic).
// S layout is b-major: S[b*512 + t].
// SHIFT=1 (pass 0): G[t+1] = u_{t+1} (skip t=T-1), G[0] = h0, S[b][0] = 1.
// SHIFT=0 (pass 1): G[t]   = u_{t+1}, all t; S[b][t] = ic_{t+1}.
//
// All stores are buffered in registers and issued once per 8-step block
// (double-buffered across blocks) so no store-source VGPR is overwritten
// before its store has long retired — removes per-step s_waitcnt vmcnt
// stalls from the scalar critical chain.
// ic is wave-uniform; lane J captures step J's ic via one v_cndmask
// (no writelane builtin on this toolchain).
template<int SHIFT>
__global__ __launch_bounds__(64, 1) void scan_wave(
    const f16* __restrict__ Win,       // [T,B,D] effective additive input, fp16
    const float* __restrict__ h0,
    f16* __restrict__ G,               // unnormalized states u
    float* __restrict__ S) {           // per-row inverse scale, b-major
  const int b = blockIdx.x;
  const int l = threadIdx.x;
  const size_t base = (size_t)b * DIMN + (size_t)l * 8;

  float u[16];
  {
    float4 a0 = *(const float4*)(h0 + base);
    float4 a1 = *(const float4*)(h0 + base + 4);
    float4 a2 = *(const float4*)(h0 + base + 512);
    float4 a3 = *(const float4*)(h0 + base + 516);
    u[0]=a0.x; u[1]=a0.y; u[2]=a0.z; u[3]=a0.w;
    u[4]=a1.x; u[5]=a1.y; u[6]=a1.z; u[7]=a1.w;
    u[8]=a2.x; u[9]=a2.y; u[10]=a2.z; u[11]=a2.w;
    u[12]=a3.x; u[13]=a3.y; u[14]=a3.z; u[15]=a3.w;
    if (SHIFT) {
      f16x8 g0, g1;
      #pragma unroll
      for (int i = 0; i < 8; ++i) { g0[i] = (f16)u[i]; g1[i] = (f16)u[i+8]; }
      *(f16x8*)(G + base) = g0;
      *(f16x8*)(G + base + 512) = g1;
      if (l == 0) S[(size_t)b * 512] = 1.0f;
    }
  }

  float c  = 1.0f;            // u = c * h
  float ic = 1.0f;            // 1/c
  float kk = 1.0f / DIMN;     // ic^2 / D

  U8 bw0[8], bw1[8];
  #pragma unroll
  for (int j = 0; j < 8; ++j) {
    bw0[j].v = *(const f16x8*)(Win + (size_t)j * BD + base);
    bw1[j].v = *(const f16x8*)(Win + (size_t)j * BD + base + 512);
  }

  U8 oa0[8], oa1[8], ob0[8], ob1[8];
  float packA = 1.0f, packB = 1.0f;

#define SCAN_STEP(J, TB, O0, O1, PK)                                         \
  {                                                                          \
    const int t_ = (TB) + (J);                                               \
    U8 w0 = bw0[J], w1 = bw1[J];                                             \
    int tn = t_ + 8; if (tn > T_STEPS - 1) tn = T_STEPS - 1;                 \
    bw0[J].v = *(const f16x8*)(Win + (size_t)tn * BD + base);                \
    bw1[J].v = *(const f16x8*)(Win + (size_t)tn * BD + base + 512);          \
    _Pragma("unroll")                                                        \
    for (int i = 0; i < 8; ++i) {                                            \
      u[i]   = fmaf(c, (float)w0.v[i], u[i]);                                \
      u[i+8] = fmaf(c, (float)w1.v[i], u[i+8]);                              \
    }                                                                        \
    float s0_=0.f, s1_=0.f, s2_=0.f, s3_=0.f;                                \
    _Pragma("unroll")                                                        \
    for (int i = 0; i < 4; ++i) {                                            \
      s0_ = fmaf(u[i],    u[i],    s0_);                                     \
      s1_ = fmaf(u[i+4],  u[i+4],  s1_);                                     \
      s2_ = fmaf(u[i+8],  u[i+8],  s2_);                                     \
      s3_ = fmaf(u[i+12], u[i+12], s3_);                                     \
    }                                                                        \
    const float Q_   = wave_allsum((s0_ + s1_) + (s2_ + s3_));               \
    const float m_   = fmaf(Q_, kk, 1e-6f);                                  \
    const float rho_ = __builtin_amdgcn_rsqf(m_);                            \
    c  = c * (m_ * rho_);                                                    \
    ic = ic * rho_;                                                          \
    kk = kk * (rho_ * rho_);                                                 \
    _Pragma("unroll")                                                        \
    for (int i = 0; i < 4; ++i) {                                            \
      O0[J].p[i] = pkrtz(u[2*i],   u[2*i+1]);                                \
      O1[J].p[i] = pkrtz(u[2*i+8], u[2*i+9]);                                \
    }                                                                        \
    PK = (l == (J)) ? ic : PK;                                               \
  }

#define SCAN_FLUSH(TB, O0, O1, PK)                                           \
  {                                                                          \
    _Pragma("unroll")                                                        \
    for (int j = 0; j < 8; ++j) {                                            \
      if (SHIFT == 0 || (TB) + j < T_STEPS - 1) {                            \
        const size_t off = (size_t)((TB) + j + SHIFT) * BD + base;           \
        *(f16x8*)(G + off)       = O0[j].v;                                  \
        *(f16x8*)(G + off + 512) = O1[j].v;                                  \
      }                                                                      \
    }                                                                        \
    const int sidx = (TB) + SHIFT + l;                                       \
    if (l < 8 && sidx < T_STEPS)                                             \
      S[(size_t)b * 512 + sidx] = PK;                                        \
  }

  for (int tb = 0; tb < T_STEPS; tb += 16) {
    #pragma unroll
    for (int j = 0; j < 8; ++j) SCAN_STEP(j, tb, oa0, oa1, packA);
    SCAN_FLUSH(tb, oa0, oa1, packA);
    #pragma unroll
    for (int j = 0; j < 8; ++j) SCAN_STEP(j, tb + 8, ob0, ob1, packB);
    SCAN_FLUSH(tb + 8, ob0, ob1, packB);
  }

#undef SCAN_STEP
#undef SCAN_FLUSH
}

// ---------- expand: g = u*ic; outs[t] = g*g*sigmoid(g), hout[t+1] = g; hout[0] = h0 ----------
__global__ __launch_bounds__(256) void expand_kernel(
    const f16* __restrict__ G1, const float* __restrict__ S1v,  // S1v b-major [B][512]
    const float* __restrict__ h0,
    float* __restrict__ outs, float* __restrict__ hout) {
  const long long total8 = (long long)T_STEPS * BD / 8;
  const long long idx = (long long)blockIdx.x * 256 + threadIdx.x;
  if (idx < total8) {
    const size_t e = (size_t)idx * 8;
    const int row = (int)(e >> 10);                    // t*BATCH + b
    const float s = S1v[((row & 31) << 9) | (row >> 5)];
    f16x8 g = *(const f16x8*)(G1 + e);
    float v[8], o[8];
    #pragma unroll
    for (int i = 0; i < 8; ++i) v[i] = (float)g[i] * s;
    #pragma unroll
    for (int i = 0; i < 8; ++i) o[i] = v[i] * v[i] / (1.0f + expf(-v[i]));
    *(float4*)(hout + BD + e)     = make_float4(v[0], v[1], v[2], v[3]);
    *(float4*)(hout + BD + e + 4) = make_float4(v[4], v[5], v[6], v[7]);
    *(float4*)(outs + e)     = make_float4(o[0], o[1], o[2], o[3]);
    *(float4*)(outs + e + 4) = make_float4(o[4], o[5], o[6], o[7]);
  } else {
    const size_t j = (size_t)(idx - total8) * 8;
    if (j < (size_t)BD) {
      float4 a0 = *(const float4*)(h0 + j);
      float4 a1 = *(const float4*)(h0 + j + 4);
      *(float4*)(hout + j)     = a0;
      *(float4*)(hout + j + 4) = a1;
    }
  }
}

extern "C" void kernel_launch(void* const* d_in, const int* in_sizes, int n_in,
                              void* d_out, int out_size, void* d_ws, size_t ws_size,
                              hipStream_t stream) {
  const float* x    = (const float*)d_in[0];
  const float* h0   = (const float*)d_in[1];
  const float* W    = (const float*)d_in[2];
  const float* Wh   = (const float*)d_in[3];
  const float* bias = (const float*)d_in[4];
  const float* la   = (const float*)d_in[5];
  const float* lb   = (const float*)d_in[6];

  char* ws = (char*)d_ws;
  f16* XH   = (f16*)(ws);
  f16* W16  = (f16*)(ws + 33554432ull);
  f16* WH16 = (f16*)(ws + 35651584ull);
  f16* WX16 = (f16*)(ws + 37748736ull);
  f16* G0   = (f16*)(ws + 71303168ull);
  f16* C16  = (f16*)(ws + 104857600ull);
  f16* G1   = XH;                               // alias: XH dead after GEMM0
  // Row-scale vectors (64 KB each, b-major [B][512]) reuse dead weight slots:
  // S0 overlaps W16  (W16 dead after GEMM0; S0 written by scan0, read by GEMM1)
  // S1 overlaps WH16 (WH16 dead after GEMM1; S1 written by scan1, read by expand)
  float* S0 = (float*)(ws + 33554432ull);
  float* S1 = (float*)(ws + 35651584ull);

  float* outs = (float*)d_out;
  float* hout = outs + (size_t)T_STEPS * BD;

  cvt_f32_f16<<<dim3((MROWS * DIMN / 8) / 256), 256, 0, stream>>>(x, XH, MROWS * DIMN / 8);
  cvt_f32_f16<<<dim3((DIMN * DIMN / 8) / 256), 256, 0, stream>>>(W, W16, DIMN * DIMN / 8);
  cvt_f32_f16<<<dim3((DIMN * DIMN / 8) / 256), 256, 0, stream>>>(Wh, WH16, DIMN * DIMN / 8);

  // WX16 = alpha * (x @ W^T + b)
  gemm_bt_f16<<<dim3(MROWS / 128, DIMN / 128), 256, 0, stream>>>(
      XH, W16, bias, WX16, la, lb, nullptr, nullptr, 0);

  // pass-0 scan: G0[t] = u0_t, S0[b][t] = ic0_t
  scan_wave<1><<<dim3(BATCH), 64, 0, stream>>>(WX16, h0, G0, S0);

  // C16 = WX16 + beta * ic0[row] * (G0 @ Wh^T)   (fused effective input for pass 1)
  gemm_bt_f16<<<dim3(MROWS / 128, DIMN / 128), 256, 0, stream>>>(
      G0, WH16, nullptr, C16, la, lb, S0, WX16, 1);

  // pass-1 scan: G1[t] = u1_{t+1}, S1[b][t] = ic1_{t+1}
  scan_wave<0><<<dim3(BATCH), 64, 0, stream>>>(C16, h0, G1, S1);

  // expand to fp32 outputs (applies ic row scale)
  const int total8 = T_STEPS * BD / 8;
  expand_kernel<<<dim3(total8 / 256 + 16), 256, 0, stream>>>(G1, S1, h0, outs, hout);
}